// Round 9
// baseline (228.939 us; speedup 1.0000x reference)
//
#include <hip/hip_runtime.h>
#include <stdint.h>

typedef __attribute__((ext_vector_type(8))) short bf16x8;
typedef __attribute__((ext_vector_type(4))) float f32x4;
typedef __attribute__((ext_vector_type(4))) unsigned short u16x4;
typedef unsigned short u16;

#define NBATCH 4
#define SEQ    4096
#define CIN    512
#define HD     64
#define OC     576      // f32 elements per out row
#define NROW   (NBATCH * SEQ)
#define AROW   1152     // u16 slots per out row; first 1024 = x-region arena

// Arena layout (u16 units inside out rows' x-regions, 1024 usable per row):
//  Q  : arena rows    0..1023  (q row r at arena row r>>4, off (r&15)*64)
//  K  : arena rows 1024..2047
//  VT : arena rows 2048..3071  (vt[batch][vc][t], 4096 t = 4 arena rows)
//  WT : arena rows 3072..3167  (wt[192][512], 2 wt rows per arena row)
// All scratch is overwritten by copyx (runs last).

__device__ __forceinline__ u16 f2b(float f) {
    union { float f; uint32_t i; } w; w.f = f;
    uint32_t r = w.i + 0x7fffu + ((w.i >> 16) & 1u);
    return (u16)(r >> 16);
}

// ---------------------------------------------------------------------------
// Kernel 1: transpose f32 weights into bf16 WT arena rows.
// ---------------------------------------------------------------------------
__global__ void prep_wt(const float* __restrict__ Wq, const float* __restrict__ Wk,
                        const float* __restrict__ Wv, u16* __restrict__ ou) {
    int row = blockIdx.x;            // 0..191
    int g = row >> 6, j = row & 63;
    const float* W = (g == 0) ? Wq : (g == 1) ? Wk : Wv;
    u16* dst = ou + (size_t)(3072 + (row >> 1)) * AROW + (row & 1) * 512;
    for (int k = threadIdx.x; k < CIN; k += blockDim.x)
        dst[k] = f2b(W[k * HD + j]);
}

// ---------------------------------------------------------------------------
// Kernel 2: QKV projection via MFMA 16x16x32 bf16 (R6 shape: no fused copy).
// Wave: 16 rows x 192 cols, K=512. q/k/vt written into the arena.
// ---------------------------------------------------------------------------
__global__ __launch_bounds__(256) void proj(
    const float* __restrict__ x,
    const float* __restrict__ bq, const float* __restrict__ bk, const float* __restrict__ bv,
    u16* __restrict__ ou)
{
    int lane = threadIdx.x & 63, wid = threadIdx.x >> 6;
    int m = lane & 15, quad = lane >> 4;
    int wg = blockIdx.x * 4 + wid;   // 0..1023
    int r0 = wg * 16;                // global row (n*SEQ + t)

    f32x4 acc[12];
#pragma unroll
    for (int i = 0; i < 12; i++) acc[i] = (f32x4){0.f, 0.f, 0.f, 0.f};

    const float* xp = x + (size_t)(r0 + m) * CIN + quad * 8;

    for (int c = 0; c < 16; c++) {
        f32x4 lo = *(const f32x4*)(xp + c * 32);
        f32x4 hi = *(const f32x4*)(xp + c * 32 + 4);
        bf16x8 a;
#pragma unroll
        for (int j = 0; j < 4; j++) { a[j] = (short)f2b(lo[j]); a[4 + j] = (short)f2b(hi[j]); }
#pragma unroll
        for (int nt = 0; nt < 12; nt++) {
            int wr = nt * 16 + m;    // wt row
            const u16* wp = ou + (size_t)(3072 + (wr >> 1)) * AROW + (wr & 1) * 512
                             + c * 32 + quad * 8;
            bf16x8 b = *(const bf16x8*)wp;
            acc[nt] = __builtin_amdgcn_mfma_f32_16x16x32_bf16(a, b, acc[nt], 0, 0, 0);
        }
    }

    int n  = r0 >> 12;          // batch
    int tl = r0 & (SEQ - 1);    // t within batch

    // q (nt 0-3), k (nt 4-7): arena rows wg / 1024+wg; C/D row=quad*4+reg, col=m
#pragma unroll
    for (int nt = 0; nt < 4; nt++) {
        int bi = nt * 16 + m;
        float biasq = bq[bi], biask = bk[bi];
#pragma unroll
        for (int reg = 0; reg < 4; reg++) {
            int rl = quad * 4 + reg;
            ou[(size_t)wg * AROW + rl * 64 + bi]          = f2b(acc[nt][reg] + biasq);
            ou[(size_t)(1024 + wg) * AROW + rl * 64 + bi] = f2b(acc[4 + nt][reg] + biask);
        }
    }
    // vt[batch][vc=bi][t]: 4 consecutive t packed (u16x4)
#pragma unroll
    for (int nt = 0; nt < 4; nt++) {
        int bi = nt * 16 + m;
        float biasv = bv[bi];
        u16x4 pk;
#pragma unroll
        for (int reg = 0; reg < 4; reg++) pk[reg] = f2b(acc[8 + nt][reg] + biasv);
        int t = tl + quad * 4;
        size_t idx = (size_t)(2048 + n * 256 + bi * 4 + (t >> 10)) * AROW + (t & 1023);
        *(u16x4*)(ou + idx) = pk;
    }
}

// ---------------------------------------------------------------------------
// Kernel 3: causal flash attention, transposed-S, 8-WAY key split.
// Block (512 thr = 8 waves) handles tiles p and 255-p sequentially; wave w
// takes key-blocks w, w+8, ... (~8.2 iters). Softmax state one scalar/lane.
// Partials merged via LDS. Reads arena (ou), writes out cols 512..575.
// ---------------------------------------------------------------------------
__global__ __launch_bounds__(512, 4) void attn(const u16* ou, float* out)
{
    __shared__ __align__(16) short plds[8][16 * 72];   // P^T per wave
    __shared__ __align__(16) float ldso[8][16][68];    // O^T partials [w][t][v]
    __shared__ float ldsm[8][16];                      // m partials
    __shared__ float ldsl[8][16];                      // l partials

    int tid = threadIdx.x;
    int lane = tid & 63, w = tid >> 6;
    int m = lane & 15, quad = lane >> 4;
    int blk = blockIdx.x;
    int batch = blk >> 7, p = blk & 127;

    const float SC = 0.125f * 1.44269504088896f;  // scale * log2(e)
    short* pw = plds[w];

    // base offsets (u16 units)
    const size_t kbase = (size_t)(1024 + batch * 256) * AROW + m * 64 + quad * 8; // + (s0/16+st)*AROW
    const int vb0 = 2048 + batch * 256 + m * 4;   // + nt*64 + (s0>>10) rows

    for (int half = 0; half < 2; half++) {
        int j = half ? (255 - p) : p;
        int t0 = j * 16;
        int nkb = (j >> 2) + 1;

        // Q B-frag: q[t0+m][quad*8..]; arena row j
        const u16* qp = ou + (size_t)(batch * 256 + j) * AROW + m * 64 + quad * 8;
        bf16x8 bq0 = *(const bf16x8*)qp;
        bf16x8 bq1 = *(const bf16x8*)(qp + 32);

        float mst = -1e30f, lst = 0.f;
        f32x4 o[4];
#pragma unroll
        for (int nt = 0; nt < 4; nt++) o[nt] = (f32x4){0.f, 0.f, 0.f, 0.f};

        int cnt = (nkb > w) ? ((nkb - w + 7) >> 3) : 0;
        int kb = w;

        // preload K A-frags for first kb (safe even if cnt==0: kb*64 <= 448)
        bf16x8 k0[4], k1[4];
#pragma unroll
        for (int st = 0; st < 4; st++) {
            const u16* kp = ou + kbase + (size_t)(kb * 4 + st) * AROW;
            k0[st] = *(const bf16x8*)kp;
            k1[st] = *(const bf16x8*)(kp + 32);
        }

        for (int it = 0; it < cnt; it++, kb += 8) {
            int s0 = kb * 64;

            // S^T = K Q^T (col = query = m, row = key_local = quad*4+reg)
            f32x4 s[4];
#pragma unroll
            for (int st = 0; st < 4; st++) {
                f32x4 a = (f32x4){0.f, 0.f, 0.f, 0.f};
                a = __builtin_amdgcn_mfma_f32_16x16x32_bf16(k0[st], bq0, a, 0, 0, 0);
                a = __builtin_amdgcn_mfma_f32_16x16x32_bf16(k1[st], bq1, a, 0, 0, 0);
                s[st] = a;
            }

            // V loads (current) + K prefetch (next) hide behind softmax VALU
            bf16x8 vf0[4], vf1[4];
            {
                int vrow = (s0 >> 10), voff = (s0 & 1023) + quad * 8;
#pragma unroll
                for (int nt = 0; nt < 4; nt++) {
                    const u16* vp = ou + (size_t)(vb0 + nt * 64 + vrow) * AROW + voff;
                    vf0[nt] = *(const bf16x8*)vp;
                    vf1[nt] = *(const bf16x8*)(vp + 32);
                }
            }
            if (it + 1 < cnt) {
                int kn = kb + 8;
#pragma unroll
                for (int st = 0; st < 4; st++) {
                    const u16* kp = ou + kbase + (size_t)(kn * 4 + st) * AROW;
                    k0[st] = *(const bf16x8*)kp;
                    k1[st] = *(const bf16x8*)(kp + 32);
                }
            }

            // scale; causal mask only on the diagonal block
            if (kb == nkb - 1) {
#pragma unroll
                for (int st = 0; st < 4; st++)
#pragma unroll
                    for (int r = 0; r < 4; r++) {
                        int key = s0 + st * 16 + quad * 4 + r;
                        s[st][r] = (key <= t0 + m) ? s[st][r] * SC : -1e30f;
                    }
            } else {
#pragma unroll
                for (int st = 0; st < 4; st++)
#pragma unroll
                    for (int r = 0; r < 4; r++) s[st][r] *= SC;
            }

            // per-query max: register tree + 2 shfl rounds
            float mx = -1e30f;
#pragma unroll
            for (int st = 0; st < 4; st++)
                mx = fmaxf(mx, fmaxf(fmaxf(s[st][0], s[st][1]), fmaxf(s[st][2], s[st][3])));
            mx = fmaxf(mx, __shfl_xor(mx, 16, 64));
            mx = fmaxf(mx, __shfl_xor(mx, 32, 64));

            float mn = fmaxf(mst, mx);
            float alpha = exp2f(mst - mn);
            mst = mn;

            float ls = 0.f;
#pragma unroll
            for (int st = 0; st < 4; st++) {
#pragma unroll
                for (int r = 0; r < 4; r++) s[st][r] = exp2f(s[st][r] - mn);
                ls += (s[st][0] + s[st][1]) + (s[st][2] + s[st][3]);
            }
            ls += __shfl_xor(ls, 16, 64);
            ls += __shfl_xor(ls, 32, 64);
            lst = lst * alpha + ls;
#pragma unroll
            for (int nt = 0; nt < 4; nt++)
#pragma unroll
                for (int r = 0; r < 4; r++) o[nt][r] *= alpha;

            // P -> LDS (row = query m, col = key_local)
#pragma unroll
            for (int st = 0; st < 4; st++) {
                u16x4 pk;
#pragma unroll
                for (int r = 0; r < 4; r++) pk[r] = f2b(s[st][r]);
                *(u16x4*)(pw + m * 72 + st * 16 + quad * 4) = pk;
            }
            __asm__ volatile("" ::: "memory");

            bf16x8 p0 = *(const bf16x8*)(pw + m * 72 + quad * 8);
            bf16x8 p1 = *(const bf16x8*)(pw + m * 72 + 32 + quad * 8);

            // O^T += V^T P^T
#pragma unroll
            for (int nt = 0; nt < 4; nt++) {
                o[nt] = __builtin_amdgcn_mfma_f32_16x16x32_bf16(vf0[nt], p0, o[nt], 0, 0, 0);
                o[nt] = __builtin_amdgcn_mfma_f32_16x16x32_bf16(vf1[nt], p1, o[nt], 0, 0, 0);
            }
        }

        // publish partials: lane holds (t = m, v = nt*16 + quad*4 + r)
        if (quad == 0) { ldsm[w][m] = mst; ldsl[w][m] = lst; }
#pragma unroll
        for (int nt = 0; nt < 4; nt++)
            *(f32x4*)&ldso[w][m][nt * 16 + quad * 4] = o[nt];
        __syncthreads();

        // merge 8 partials: thread tau<256 -> (t = tau>>4, v = (tau&15)*4..+3)
        if (tid < 256) {
            int t = tid >> 4, vg = tid & 15;
            float mmax = -1e30f;
#pragma unroll
            for (int w8 = 0; w8 < 8; w8++) mmax = fmaxf(mmax, ldsm[w8][t]);
            float L = 0.f;
            f32x4 racc = (f32x4){0.f, 0.f, 0.f, 0.f};
#pragma unroll
            for (int w8 = 0; w8 < 8; w8++) {
                float c = exp2f(ldsm[w8][t] - mmax);
                L += ldsl[w8][t] * c;
                f32x4 ov = *(const f32x4*)&ldso[w8][t][vg * 4];
#pragma unroll
                for (int i = 0; i < 4; i++) racc[i] += ov[i] * c;
            }
            float inv = 1.0f / L;
            f32x4 res;
#pragma unroll
            for (int i = 0; i < 4; i++) res[i] = racc[i] * inv;
            *(f32x4*)(out + (size_t)(batch * SEQ + t0 + t) * OC + CIN + vg * 4) = res;
        }
        __syncthreads();   // LDS reused for second tile
    }
}

// ---------------------------------------------------------------------------
// Kernel 4: out[:, :512] = x (exact f32 copy), overwriting the arena. LAST.
// ---------------------------------------------------------------------------
__global__ __launch_bounds__(64) void copyx(const float* __restrict__ x, float* __restrict__ out)
{
    int lane = threadIdx.x;
    size_t r = blockIdx.x;
    const float* xp = x + r * CIN + lane * 8;
    float* op = out + r * OC + lane * 8;
    f32x4 lo = *(const f32x4*)(xp);
    f32x4 hi = *(const f32x4*)(xp + 4);
    *(f32x4*)(op)     = lo;
    *(f32x4*)(op + 4) = hi;
}

// ---------------------------------------------------------------------------
extern "C" void kernel_launch(void* const* d_in, const int* in_sizes, int n_in,
                              void* d_out, int out_size, void* d_ws, size_t ws_size,
                              hipStream_t stream) {
    const float* x  = (const float*)d_in[0];
    const float* Wq = (const float*)d_in[1];
    const float* bq = (const float*)d_in[2];
    const float* Wk = (const float*)d_in[3];
    const float* bk = (const float*)d_in[4];
    const float* Wv = (const float*)d_in[5];
    const float* bv = (const float*)d_in[6];
    float* out = (float*)d_out;
    u16* ou = (u16*)d_out;           // arena view

    (void)d_ws; (void)ws_size;       // d_ws intentionally unused (R8 post-mortem)

    prep_wt<<<dim3(192), dim3(256), 0, stream>>>(Wq, Wk, Wv, ou);
    proj<<<dim3(256), dim3(256), 0, stream>>>(x, bq, bk, bv, ou);
    attn<<<dim3(512), dim3(512), 0, stream>>>(ou, out);
    copyx<<<dim3(NROW), dim3(64), 0, stream>>>(x, out);
}